// Round 5
// baseline (601.999 us; speedup 1.0000x reference)
//
#include <hip/hip_runtime.h>

// decoderLayer B=8, L=1024, E=1024, H=16, dk=64. fp32 I/O, bf16 internals,
// fp32 accum via bf16 MFMA 16x16x32. m97-style async global_load_lds staging
// into fragment-ordered LDS (all ds_read_b128 lane-linear, conflict-free).
// ws: 8 transposed bf16 weights (16MB) + 4 bf16 activation buffers (64MB).

typedef unsigned short u16;
typedef unsigned int u32;
typedef __attribute__((ext_vector_type(8))) short bf16x8;
typedef __attribute__((ext_vector_type(4))) float f32x4;

#define Bv 8
#define Lv 1024
#define Ev 1024
#define Hv 16
#define DKv 64
#define Mv (Bv * Lv)

#if defined(__has_builtin)
# if __has_builtin(__builtin_amdgcn_global_load_lds)
#  define HAS_GLL 1
# endif
#endif
#ifndef HAS_GLL
# define HAS_GLL 0
#endif

#if HAS_GLL
// async 16B/lane global->LDS; LDS dest = wave-uniform base + lane*16
__device__ __forceinline__ void gll16(const u16* g, u16* l) {
    __builtin_amdgcn_global_load_lds(
        (const __attribute__((address_space(1))) void*)(unsigned long long)(g),
        (__attribute__((address_space(3))) void*)(unsigned)(unsigned long long)(l),
        16, 0, 0);
}
#endif

__device__ __forceinline__ u16 f2bf(float f) {
    u32 u = __float_as_uint(f);
    u += 0x7fffu + ((u >> 16) & 1u);
    return (u16)(u >> 16);
}
__device__ __forceinline__ u32 pack2(float a, float b) {
    u32 ua = __float_as_uint(a); ua += 0x7fffu + ((ua >> 16) & 1u);
    u32 ub = __float_as_uint(b); ub += 0x7fffu + ((ub >> 16) & 1u);
    return (ua >> 16) | (ub & 0xffff0000u);
}
__device__ __forceinline__ float bf_lo(u32 u) { return __uint_as_float(u << 16); }
__device__ __forceinline__ float bf_hi(u32 u) { return __uint_as_float(u & 0xffff0000u); }

// fp32 -> bf16 convert
__global__ __launch_bounds__(256) void conv_k(const float* __restrict__ s, u16* __restrict__ d) {
    int i4 = (blockIdx.x * 256 + threadIdx.x) * 4;
    float4 v = *(const float4*)(s + i4);
    uint2 o = {pack2(v.x, v.y), pack2(v.z, v.w)};
    *(uint2*)(d + i4) = o;
}

// attn weight (H,E,dk) fp32 -> Wt[n=h*64+d][k=e] bf16
__global__ __launch_bounds__(256) void trans_attn(const float* __restrict__ s, u16* __restrict__ d) {
    __shared__ float t[32][33];
    const int d0 = blockIdx.x * 32, e0 = blockIdx.y * 32, h = blockIdx.z;
    const int tx = threadIdx.x, ty = threadIdx.y;
#pragma unroll
    for (int i = 0; i < 4; i++)
        t[ty + i * 8][tx] = s[(size_t)h * Ev * DKv + (size_t)(e0 + ty + i * 8) * DKv + d0 + tx];
    __syncthreads();
#pragma unroll
    for (int i = 0; i < 4; i++)
        d[(size_t)(h * DKv + d0 + ty + i * 8) * Ev + e0 + tx] = f2bf(t[tx][ty + i * 8]);
}

// fc weight (E,E) [k][n] fp32 -> Wt[n][k] bf16
__global__ __launch_bounds__(256) void trans_fc(const float* __restrict__ s, u16* __restrict__ d) {
    __shared__ float t[32][33];
    const int n0 = blockIdx.x * 32, k0 = blockIdx.y * 32;
    const int tx = threadIdx.x, ty = threadIdx.y;
#pragma unroll
    for (int i = 0; i < 4; i++)
        t[ty + i * 8][tx] = s[(size_t)(k0 + ty + i * 8) * Ev + n0 + tx];
    __syncthreads();
#pragma unroll
    for (int i = 0; i < 4; i++)
        d[(size_t)(n0 + ty + i * 8) * Ev + k0 + tx] = f2bf(t[tx][ty + i * 8]);
}

// ---- MFMA GEMM, 128x128 tile, BK=64, async frag-ordered staging.
//      Fused N: which = col0>>10 routes to O0/O1/O2; TRANSW = which-index
//      written transposed [n][M] (for V), -1 = none. ----
template <int BIAS, int RELU, int TRANSW>
__global__ __launch_bounds__(256) void mgemm(const u16* __restrict__ A,
                                             const u16* __restrict__ Wt,
                                             const float* __restrict__ bias,
                                             u16* __restrict__ O0, u16* __restrict__ O1,
                                             u16* __restrict__ O2,
                                             const int* __restrict__ lens) {
    __shared__ u16 Alds[16 * 512];
    __shared__ u16 Blds[16 * 512];
    const int tid = threadIdx.x;
    const int w = tid >> 6, l = tid & 63;
    const int lc = l & 15, lq = l >> 4;
    const int row0 = blockIdx.y * 128, col0 = blockIdx.x * 128;
    const int which = col0 >> 10, colL = col0 & 1023;
    u16* C = (which == 0) ? O0 : (which == 1 ? O1 : O2);
    const int wm4 = (w >> 1) * 4, wn4 = (w & 1) * 4;

    f32x4 acc[4][4];
#pragma unroll
    for (int i = 0; i < 4; i++)
#pragma unroll
        for (int j = 0; j < 4; j++) acc[i][j] = (f32x4){0.f, 0.f, 0.f, 0.f};

    // staging bases: wave w stages A blocks 4w..4w+3, B blocks 4w..4w+3
    const u16* Ag[4]; const u16* Bg[4]; u16* Al[4]; u16* Bl[4];
#pragma unroll
    for (int i = 0; i < 4; i++) {
        const int g16 = 2 * w + (i >> 1), k32 = i & 1;
        Ag[i] = A  + (size_t)(row0 + g16 * 16 + lc) * Ev + k32 * 32 + lq * 8;
        Bg[i] = Wt + (size_t)(col0 + g16 * 16 + lc) * Ev + k32 * 32 + lq * 8;
        Al[i] = Alds + (g16 * 2 + k32) * 512;
        Bl[i] = Blds + (g16 * 2 + k32) * 512;
    }

    for (int k0 = 0; k0 < Ev; k0 += 64) {
#if HAS_GLL
#pragma unroll
        for (int i = 0; i < 4; i++) { gll16(Ag[i], Al[i]); gll16(Bg[i], Bl[i]); }
#else
#pragma unroll
        for (int i = 0; i < 4; i++) {
            *(uint4*)(Al[i] + l * 8) = *(const uint4*)Ag[i];
            *(uint4*)(Bl[i] + l * 8) = *(const uint4*)Bg[i];
        }
#endif
#pragma unroll
        for (int i = 0; i < 4; i++) { Ag[i] += 64; Bg[i] += 64; }
        __syncthreads();
#pragma unroll
        for (int km = 0; km < 2; km++) {
            bf16x8 af[4], bfr[4];
#pragma unroll
            for (int mt = 0; mt < 4; mt++)
                af[mt] = *(const bf16x8*)(Alds + ((wm4 + mt) * 2 + km) * 512 + l * 8);
#pragma unroll
            for (int nt = 0; nt < 4; nt++)
                bfr[nt] = *(const bf16x8*)(Blds + ((wn4 + nt) * 2 + km) * 512 + l * 8);
#pragma unroll
            for (int mt = 0; mt < 4; mt++)
#pragma unroll
                for (int nt = 0; nt < 4; nt++)
                    acc[mt][nt] = __builtin_amdgcn_mfma_f32_16x16x32_bf16(
                        af[mt], bfr[nt], acc[mt][nt], 0, 0, 0);
        }
        __syncthreads();
    }

    int len = lens[row0 >> 10];
    len = min(max(len, 0), Lv);
    const bool tr = (TRANSW == which);
    float bv[4];
#pragma unroll
    for (int nt = 0; nt < 4; nt++)
        bv[nt] = BIAS ? bias[colL + wn4 * 16 + nt * 16 + lc] : 0.f;

#pragma unroll
    for (int mt = 0; mt < 4; mt++) {
        const int rowb = row0 + wm4 * 16 + mt * 16 + lq * 4;
#pragma unroll
        for (int nt = 0; nt < 4; nt++) {
            const int col = colL + wn4 * 16 + nt * 16 + lc;
            float v[4];
#pragma unroll
            for (int r = 0; r < 4; r++) {
                float x = acc[mt][nt][r] + bv[nt];
                if (RELU) x = fmaxf(x, 0.f);
                v[r] = (((rowb + r) & (Lv - 1)) >= len) ? 0.f : x;
            }
            if (tr) {
                uint2 o = {pack2(v[0], v[1]), pack2(v[2], v[3])};
                *(uint2*)(C + (size_t)col * Mv + rowb) = o;
            } else {
#pragma unroll
                for (int r = 0; r < 4; r++)
                    C[(size_t)(rowb + r) * Ev + col] = f2bf(v[r]);
            }
        }
    }
}

// ---- MFMA flash attention. 128 q/block, 4 waves x 32 q (2 m-tiles), 128-key
//      tiles, K/V/P fragment-ordered LDS, async staging, online softmax.
//      QZ [row][E] bf16 (in-place out), K [row][E] bf16, VT [n][M] bf16. ----
template <int CAUSAL>
__global__ __launch_bounds__(256) void mattn(u16* __restrict__ QZ,
                                             const u16* __restrict__ K,
                                             const u16* __restrict__ VT,
                                             const int* __restrict__ lens) {
    __shared__ u16 Kt[16 * 512];     // 16KB: blocks (key16*2 + d32)
    __shared__ u16 Vt[16 * 512];     // 16KB: blocks (d16*4 + key32)
    __shared__ u16 Pt[4 * 4 * 512];  // 16KB: per-wave 4 blocks (key32), one m-tile
    const int b = blockIdx.z, h = blockIdx.y, qb = blockIdx.x;
    const int q0 = qb * 128;
    const int tid = threadIdx.x;
    const int w = tid >> 6, l = tid & 63;
    const int lc = l & 15, lq = l >> 4;
    int len = lens[b];
    len = min(max(len, 0), Lv);

    if (q0 >= len) { // fully masked: zero Z rows
        const int zr = tid >> 1, zc = (tid & 1) * 32;
        uint4 z4 = {0u, 0u, 0u, 0u};
        uint4* p = (uint4*)(QZ + (size_t)(b * Lv + q0 + zr) * Ev + h * DKv + zc);
        p[0] = z4; p[1] = z4; p[2] = z4; p[3] = z4;
        return;
    }

    // Q fragments: wave w owns q rows [q0+w*32, +32) = m-tiles mt 0,1
    bf16x8 qf[2][2];
#pragma unroll
    for (int mt = 0; mt < 2; mt++)
#pragma unroll
        for (int k2 = 0; k2 < 2; k2++)
            qf[mt][k2] = *(const bf16x8*)(QZ + (size_t)(b * Lv + q0 + w * 32 + mt * 16 + lc) * Ev +
                                          h * DKv + k2 * 32 + lq * 8);

    f32x4 of[2][4];
#pragma unroll
    for (int mt = 0; mt < 2; mt++)
#pragma unroll
        for (int nd = 0; nd < 4; nd++) of[mt][nd] = (f32x4){0.f, 0.f, 0.f, 0.f};
    float mrow[2][4], lrow[2][4];
#pragma unroll
    for (int mt = 0; mt < 2; mt++)
#pragma unroll
        for (int r = 0; r < 4; r++) { mrow[mt][r] = -1e30f; lrow[mt][r] = 0.f; }

    // staging bases: wave w stages K blocks 4w..4w+3, V blocks (w*4 + 0..3)
    const u16* Kg[4]; const u16* Vg[4]; u16* Kl[4]; u16* Vl[4];
#pragma unroll
    for (int i = 0; i < 4; i++) {
        const int k16 = 2 * w + (i >> 1), d32 = i & 1;
        Kg[i] = K + (size_t)(b * Lv + k16 * 16 + lc) * Ev + h * DKv + d32 * 32 + lq * 8;
        Kl[i] = Kt + (k16 * 2 + d32) * 512;
        Vg[i] = VT + (size_t)(h * DKv + w * 16 + lc) * Mv + b * Lv + i * 32 + lq * 8;
        Vl[i] = Vt + (w * 4 + i) * 512;
    }
    u16* Pw = Pt + w * 2048;

    const int jend = CAUSAL ? min(len, q0 + 128) : len;
    const int ntiles = (jend + 127) >> 7;

    for (int kt = 0; kt < ntiles; kt++) {
        const int koff = kt * 128;
#if HAS_GLL
#pragma unroll
        for (int i = 0; i < 4; i++) {
            gll16(Kg[i] + (size_t)koff * Ev, Kl[i]);
            gll16(Vg[i] + koff, Vl[i]);
        }
#else
#pragma unroll
        for (int i = 0; i < 4; i++) {
            *(uint4*)(Kl[i] + l * 8) = *(const uint4*)(Kg[i] + (size_t)koff * Ev);
            *(uint4*)(Vl[i] + l * 8) = *(const uint4*)(Vg[i] + koff);
        }
#endif
        __syncthreads();

        // S = Q K^T : sf[mt][nt], keys nt*16+lc, q = w*32+mt*16+lq*4+r
        f32x4 sf[2][8];
#pragma unroll
        for (int nt = 0; nt < 8; nt++) {
            bf16x8 kf0 = *(const bf16x8*)(Kt + (nt * 2 + 0) * 512 + l * 8);
            bf16x8 kf1 = *(const bf16x8*)(Kt + (nt * 2 + 1) * 512 + l * 8);
#pragma unroll
            for (int mt = 0; mt < 2; mt++) {
                f32x4 s = (f32x4){0.f, 0.f, 0.f, 0.f};
                s = __builtin_amdgcn_mfma_f32_16x16x32_bf16(qf[mt][0], kf0, s, 0, 0, 0);
                s = __builtin_amdgcn_mfma_f32_16x16x32_bf16(qf[mt][1], kf1, s, 0, 0, 0);
                sf[mt][nt] = s;
            }
        }

        float alpha[2][4];
#pragma unroll
        for (int mt = 0; mt < 2; mt++) {
            float tmax[4] = {-1e30f, -1e30f, -1e30f, -1e30f};
#pragma unroll
            for (int nt = 0; nt < 8; nt++) {
                const int jj = koff + nt * 16 + lc;
                const bool jv = jj < len;
#pragma unroll
                for (int r = 0; r < 4; r++) {
                    const int iq = q0 + w * 32 + mt * 16 + lq * 4 + r;
                    const bool valid = jv && (!CAUSAL || jj <= iq);
                    float e = valid ? sf[mt][nt][r] * 0.125f : -1e30f;
                    sf[mt][nt][r] = e;
                    tmax[r] = fmaxf(tmax[r], e);
                }
            }
#pragma unroll
            for (int r = 0; r < 4; r++) {
#pragma unroll
                for (int d = 1; d < 16; d <<= 1)
                    tmax[r] = fmaxf(tmax[r], __shfl_xor(tmax[r], d, 64));
            }
            float psum[4];
#pragma unroll
            for (int r = 0; r < 4; r++) {
                const float mn = fmaxf(mrow[mt][r], tmax[r]);
                alpha[mt][r] = __expf(mrow[mt][r] - mn);
                mrow[mt][r] = mn;
                psum[r] = 0.f;
            }
#pragma unroll
            for (int nt = 0; nt < 8; nt++)
#pragma unroll
                for (int r = 0; r < 4; r++) {
                    float p = __expf(sf[mt][nt][r] - mrow[mt][r]);
                    sf[mt][nt][r] = p;
                    psum[r] += p;
                }
#pragma unroll
            for (int r = 0; r < 4; r++) {
#pragma unroll
                for (int d = 1; d < 16; d <<= 1) psum[r] += __shfl_xor(psum[r], d, 64);
                lrow[mt][r] = lrow[mt][r] * alpha[mt][r] + psum[r];
            }
#pragma unroll
            for (int nd = 0; nd < 4; nd++)
#pragma unroll
                for (int r = 0; r < 4; r++) of[mt][nd][r] *= alpha[mt][r];
        }

        // PV per m-tile (P buffer reused sequentially)
#pragma unroll
        for (int mt = 0; mt < 2; mt++) {
#pragma unroll
            for (int nt = 0; nt < 8; nt++)
#pragma unroll
                for (int r = 0; r < 4; r++)
                    Pw[(nt >> 1) * 512 +
                       ((2 * (nt & 1) + (lc >> 3)) * 16 + lq * 4 + r) * 8 + (lc & 7)] =
                        f2bf(sf[mt][nt][r]);
#pragma unroll
            for (int km = 0; km < 4; km++) {
                bf16x8 pa = *(const bf16x8*)(Pw + km * 512 + l * 8);
#pragma unroll
                for (int nd = 0; nd < 4; nd++) {
                    bf16x8 vb = *(const bf16x8*)(Vt + (nd * 4 + km) * 512 + l * 8);
                    of[mt][nd] = __builtin_amdgcn_mfma_f32_16x16x32_bf16(pa, vb, of[mt][nd], 0, 0, 0);
                }
            }
        }
        __syncthreads();
    }

#pragma unroll
    for (int mt = 0; mt < 2; mt++) {
        float inv[4];
#pragma unroll
        for (int r = 0; r < 4; r++) {
            const int iq = q0 + w * 32 + mt * 16 + lq * 4 + r;
            inv[r] = (iq < len && lrow[mt][r] > 0.f) ? (1.f / lrow[mt][r]) : 0.f;
        }
#pragma unroll
        for (int nd = 0; nd < 4; nd++)
#pragma unroll
            for (int r = 0; r < 4; r++)
                QZ[(size_t)(b * Lv + q0 + w * 32 + mt * 16 + lq * 4 + r) * Ev +
                   h * DKv + nd * 16 + lc] = f2bf(of[mt][nd][r] * inv[r]);
    }
}

// ---- residual + LayerNorm: out = LN(base + z)*g + b. z bf16. ----
template <int BASEBF, int OUTF32>
__global__ __launch_bounds__(256) void ln_k(const void* __restrict__ base,
                                            const u16* __restrict__ z,
                                            const float* __restrict__ g,
                                            const float* __restrict__ bta,
                                            void* __restrict__ out) {
    __shared__ float r1[256], r2[256];
    const int row = blockIdx.x, t = threadIdx.x;
    const int c0 = t * 4;
    float v[4];
    if (BASEBF) {
        uint2 bu = *(const uint2*)((const u16*)base + (size_t)row * Ev + c0);
        v[0] = bf_lo(bu.x); v[1] = bf_hi(bu.x); v[2] = bf_lo(bu.y); v[3] = bf_hi(bu.y);
    } else {
        float4 f = *(const float4*)((const float*)base + (size_t)row * Ev + c0);
        v[0] = f.x; v[1] = f.y; v[2] = f.z; v[3] = f.w;
    }
    uint2 zu = *(const uint2*)(z + (size_t)row * Ev + c0);
    v[0] += bf_lo(zu.x); v[1] += bf_hi(zu.x); v[2] += bf_lo(zu.y); v[3] += bf_hi(zu.y);
    r1[t] = v[0] + v[1] + v[2] + v[3];
    r2[t] = v[0] * v[0] + v[1] * v[1] + v[2] * v[2] + v[3] * v[3];
    __syncthreads();
    for (int s = 128; s > 0; s >>= 1) {
        if (t < s) { r1[t] += r1[t + s]; r2[t] += r2[t + s]; }
        __syncthreads();
    }
    const float mu = r1[0] * (1.f / Ev);
    const float var = r2[0] * (1.f / Ev) - mu * mu;
    const float rinv = rsqrtf(fmaxf(var, 0.f) + 1e-5f);
    float4 gv = *(const float4*)(g + c0);
    float4 bv = *(const float4*)(bta + c0);
    float y[4];
    y[0] = (v[0] - mu) * rinv * gv.x + bv.x;
    y[1] = (v[1] - mu) * rinv * gv.y + bv.y;
    y[2] = (v[2] - mu) * rinv * gv.z + bv.z;
    y[3] = (v[3] - mu) * rinv * gv.w + bv.w;
    if (OUTF32) {
        float4 ow = {y[0], y[1], y[2], y[3]};
        *(float4*)((float*)out + (size_t)row * Ev + c0) = ow;
    } else {
        uint2 ow = {pack2(y[0], y[1]), pack2(y[2], y[3])};
        *(uint2*)((u16*)out + (size_t)row * Ev + c0) = ow;
    }
}

extern "C" void kernel_launch(void* const* d_in, const int* in_sizes, int n_in,
                              void* d_out, int out_size, void* d_ws, size_t ws_size,
                              hipStream_t stream) {
    const float* x    = (const float*)d_in[0];
    const float* ctx  = (const float*)d_in[1];
    const int*   lens = (const int*)d_in[2];
    const float* Wq1 = (const float*)d_in[4];
    const float* Wk1 = (const float*)d_in[5];
    const float* Wv1 = (const float*)d_in[6];
    const float* Wq2 = (const float*)d_in[7];
    const float* Wk2 = (const float*)d_in[8];
    const float* Wv2 = (const float*)d_in[9];
    const float* g1 = (const float*)d_in[10], *b1 = (const float*)d_in[11];
    const float* g2 = (const float*)d_in[12], *b2 = (const float*)d_in[13];
    const float* g3 = (const float*)d_in[14], *b3 = (const float*)d_in[15];
    const float* fc1w = (const float*)d_in[16], *fc1b = (const float*)d_in[17];
    const float* fc2w = (const float*)d_in[18], *fc2b = (const float*)d_in[19];

    const size_t WSZ = (size_t)Ev * Ev;
    const size_t MM  = (size_t)Mv * Ev;
    u16* WT = (u16*)d_ws;                // q1,k1,v1,q2,k2,v2,f1,f2 (contiguous!)
    u16* Wtq1 = WT + 0 * WSZ, *Wtk1 = WT + 1 * WSZ, *Wtv1 = WT + 2 * WSZ;
    u16* Wtq2 = WT + 3 * WSZ, *Wtk2 = WT + 4 * WSZ, *Wtv2 = WT + 5 * WSZ;
    u16* Wtf1 = WT + 6 * WSZ, *Wtf2 = WT + 7 * WSZ;
    u16* B1 = WT + 8 * WSZ;
    u16* B2 = B1 + MM;
    u16* B3 = B2 + MM;
    u16* B4 = B3 + MM;
    u16* xb = (u16*)d_out;               // bf16 x/ctx parked in d_out until final LN
    u16* cb = xb + MM;

    dim3 gC(Mv * Ev / 1024), gTA(2, 32, Hv), gTF(32, 32), bT(32, 8);
    dim3 gQKV(24, 64), gQK(16, 64), gG1(8, 64), gA(8, Hv, Bv), gL(Mv);

    conv_k<<<gC, 256, 0, stream>>>(x, xb);
    conv_k<<<gC, 256, 0, stream>>>(ctx, cb);
    trans_attn<<<gTA, bT, 0, stream>>>(Wq1, Wtq1);
    trans_attn<<<gTA, bT, 0, stream>>>(Wk1, Wtk1);
    trans_attn<<<gTA, bT, 0, stream>>>(Wv1, Wtv1);
    trans_attn<<<gTA, bT, 0, stream>>>(Wq2, Wtq2);
    trans_attn<<<gTA, bT, 0, stream>>>(Wk2, Wtk2);
    trans_attn<<<gTA, bT, 0, stream>>>(Wv2, Wtv2);
    trans_fc<<<gTF, bT, 0, stream>>>(fc1w, Wtf1);
    trans_fc<<<gTF, bT, 0, stream>>>(fc2w, Wtf2);

    // self-attention (causal): fused Q/K/V^T projection, then flash
    mgemm<0, 0, 2><<<gQKV, 256, 0, stream>>>(xb, Wtq1, nullptr, B1, B2, B3, lens);
    mattn<1><<<gA, 256, 0, stream>>>(B1, B2, B3, lens);                 // Z1 -> B1
    ln_k<0, 0><<<gL, 256, 0, stream>>>(x, B1, g1, b1, B2);              // X1 -> B2

    // cross-attention: fused Q/K from ctx; V^T from X1
    mgemm<0, 0, -1><<<gQK, 256, 0, stream>>>(cb, Wtq2, nullptr, B1, B3, nullptr, lens);
    mgemm<0, 0, 0><<<gG1, 256, 0, stream>>>(B2, Wtv2, nullptr, B4, nullptr, nullptr, lens);
    mattn<0><<<gA, 256, 0, stream>>>(B1, B3, B4, lens);                 // Z2 -> B1
    ln_k<1, 0><<<gL, 256, 0, stream>>>(B2, B1, g2, b2, B3);             // X2 -> B3

    // FFN
    mgemm<1, 1, -1><<<gG1, 256, 0, stream>>>(B3, Wtf1, fc1b, B1, nullptr, nullptr, lens); // H
    mgemm<1, 0, -1><<<gG1, 256, 0, stream>>>(B1, Wtf2, fc2b, B2, nullptr, nullptr, lens); // Z3
    ln_k<1, 1><<<gL, 256, 0, stream>>>(B3, B2, g3, b3, d_out);          // final (fp32)
}

// Round 6
// 539.883 us; speedup vs baseline: 1.1151x; 1.1151x over previous
//
#include <hip/hip_runtime.h>

// decoderLayer B=8, L=1024, E=1024, H=16, dk=64. fp32 I/O, bf16 internals,
// fp32 accum via bf16 MFMA 16x16x32. m97-style async global_load_lds staging,
// fragment-ordered LDS (conflict-free). NEW: masked-row-block skip in GEMM
// (out_mask zeroes ~50% of rows -> skip K-loop), single fused prep kernel,
// shuffle-based LayerNorm reduction.

typedef unsigned short u16;
typedef unsigned int u32;
typedef __attribute__((ext_vector_type(8))) short bf16x8;
typedef __attribute__((ext_vector_type(4))) float f32x4;

#define Bv 8
#define Lv 1024
#define Ev 1024
#define Hv 16
#define DKv 64
#define Mv (Bv * Lv)

#if defined(__has_builtin)
# if __has_builtin(__builtin_amdgcn_global_load_lds)
#  define HAS_GLL 1
# endif
#endif
#ifndef HAS_GLL
# define HAS_GLL 0
#endif

#if HAS_GLL
__device__ __forceinline__ void gll16(const u16* g, u16* l) {
    __builtin_amdgcn_global_load_lds(
        (const __attribute__((address_space(1))) void*)(unsigned long long)(g),
        (__attribute__((address_space(3))) void*)(unsigned)(unsigned long long)(l),
        16, 0, 0);
}
#endif

__device__ __forceinline__ u16 f2bf(float f) {
    u32 u = __float_as_uint(f);
    u += 0x7fffu + ((u >> 16) & 1u);
    return (u16)(u >> 16);
}
__device__ __forceinline__ u32 pack2(float a, float b) {
    u32 ua = __float_as_uint(a); ua += 0x7fffu + ((ua >> 16) & 1u);
    u32 ub = __float_as_uint(b); ub += 0x7fffu + ((ub >> 16) & 1u);
    return (ua >> 16) | (ub & 0xffff0000u);
}
__device__ __forceinline__ float bf_lo(u32 u) { return __uint_as_float(u << 16); }
__device__ __forceinline__ float bf_hi(u32 u) { return __uint_as_float(u & 0xffff0000u); }

// ---- fused prep: conv x, conv ctx, 6 attn-weight transposes, 2 fc transposes.
//      Routed by blockIdx.x; 256 threads. ----
__global__ __launch_bounds__(256) void prep_k(
    const float* __restrict__ x, const float* __restrict__ ctx,
    const float* __restrict__ wq1, const float* __restrict__ wk1, const float* __restrict__ wv1,
    const float* __restrict__ wq2, const float* __restrict__ wk2, const float* __restrict__ wv2,
    const float* __restrict__ f1, const float* __restrict__ f2,
    u16* __restrict__ xb, u16* __restrict__ cb, u16* __restrict__ WT) {
    const int id = blockIdx.x, t = threadIdx.x;
    if (id < 16384) { // conv x / ctx
        const float* s = (id < 8192) ? x : ctx;
        u16* d = (id < 8192) ? xb : cb;
        const int i4 = ((id & 8191) * 256 + t) * 4;
        float4 v = *(const float4*)(s + i4);
        uint2 o = {pack2(v.x, v.y), pack2(v.z, v.w)};
        *(uint2*)(d + i4) = o;
        return;
    }
    __shared__ float tl[32][33];
    const int tx = t & 31, ty = t >> 5;
    if (id < 16384 + 6144) { // attn weight (H,E,dk) -> Wt[h*64+d][e]
        const int wi = (id - 16384) >> 10;
        const int tile = (id - 16384) & 1023;
        const float* s = (wi == 0) ? wq1 : (wi == 1) ? wk1 : (wi == 2) ? wv1
                       : (wi == 3) ? wq2 : (wi == 4) ? wk2 : wv2;
        u16* d = WT + (size_t)wi * Ev * Ev;
        const int h = tile >> 6, rem = tile & 63;
        const int d0 = (rem & 1) * 32, e0 = (rem >> 1) * 32;
#pragma unroll
        for (int i = 0; i < 4; i++)
            tl[ty + i * 8][tx] = s[(size_t)h * Ev * DKv + (size_t)(e0 + ty + i * 8) * DKv + d0 + tx];
        __syncthreads();
#pragma unroll
        for (int i = 0; i < 4; i++)
            d[(size_t)(h * DKv + d0 + ty + i * 8) * Ev + e0 + tx] = f2bf(tl[tx][ty + i * 8]);
    } else { // fc weight (E,E)[k][n] -> Wt[n][k]
        const int wi = (id - 16384 - 6144) >> 10;
        const int tile = (id - 16384 - 6144) & 1023;
        const float* s = wi ? f2 : f1;
        u16* d = WT + (size_t)(6 + wi) * Ev * Ev;
        const int n0 = (tile & 31) * 32, k0 = (tile >> 5) * 32;
#pragma unroll
        for (int i = 0; i < 4; i++)
            tl[ty + i * 8][tx] = s[(size_t)(k0 + ty + i * 8) * Ev + n0 + tx];
        __syncthreads();
#pragma unroll
        for (int i = 0; i < 4; i++)
            d[(size_t)(n0 + ty + i * 8) * Ev + k0 + tx] = f2bf(tl[tx][ty + i * 8]);
    }
}

// ---- MFMA GEMM, 128x128 tile, BK=64, async frag-ordered staging.
//      Fused N: which = col0>>10 routes to O0/O1/O2; TRANSW = which-index
//      written transposed [n][M] (for V), -1 = none.
//      Fully-masked row-blocks ((row0%1024)>=len) zero-fill and exit. ----
template <int BIAS, int RELU, int TRANSW>
__global__ __launch_bounds__(256) void mgemm(const u16* __restrict__ A,
                                             const u16* __restrict__ Wt,
                                             const float* __restrict__ bias,
                                             u16* __restrict__ O0, u16* __restrict__ O1,
                                             u16* __restrict__ O2,
                                             const int* __restrict__ lens) {
    __shared__ u16 Alds[16 * 512];
    __shared__ u16 Blds[16 * 512];
    const int tid = threadIdx.x;
    const int w = tid >> 6, l = tid & 63;
    const int lc = l & 15, lq = l >> 4;
    const int row0 = blockIdx.y * 128, col0 = blockIdx.x * 128;
    const int which = col0 >> 10, colL = col0 & 1023;
    u16* C = (which == 0) ? O0 : (which == 1 ? O1 : O2);
    const bool tr = (TRANSW == which);

    int len = lens[row0 >> 10];
    len = min(max(len, 0), Lv);
    if ((row0 & (Lv - 1)) >= len) { // whole 128-row block masked -> zeros
        const int rr = tid >> 1, cc = (tid & 1) * 64;
        u16* p = tr ? C + (size_t)(colL + rr) * Mv + row0 + cc
                    : C + (size_t)(row0 + rr) * Ev + colL + cc;
        uint4 z4 = {0u, 0u, 0u, 0u};
#pragma unroll
        for (int i = 0; i < 8; i++) *(uint4*)(p + i * 8) = z4;
        return;
    }

    const int wm4 = (w >> 1) * 4, wn4 = (w & 1) * 4;
    f32x4 acc[4][4];
#pragma unroll
    for (int i = 0; i < 4; i++)
#pragma unroll
        for (int j = 0; j < 4; j++) acc[i][j] = (f32x4){0.f, 0.f, 0.f, 0.f};

    const u16* Ag[4]; const u16* Bg[4]; u16* Al[4]; u16* Bl[4];
#pragma unroll
    for (int i = 0; i < 4; i++) {
        const int g16 = 2 * w + (i >> 1), k32 = i & 1;
        Ag[i] = A  + (size_t)(row0 + g16 * 16 + lc) * Ev + k32 * 32 + lq * 8;
        Bg[i] = Wt + (size_t)(col0 + g16 * 16 + lc) * Ev + k32 * 32 + lq * 8;
        Al[i] = Alds + (g16 * 2 + k32) * 512;
        Bl[i] = Blds + (g16 * 2 + k32) * 512;
    }

    for (int k0 = 0; k0 < Ev; k0 += 64) {
#if HAS_GLL
#pragma unroll
        for (int i = 0; i < 4; i++) { gll16(Ag[i], Al[i]); gll16(Bg[i], Bl[i]); }
#else
#pragma unroll
        for (int i = 0; i < 4; i++) {
            *(uint4*)(Al[i] + l * 8) = *(const uint4*)Ag[i];
            *(uint4*)(Bl[i] + l * 8) = *(const uint4*)Bg[i];
        }
#endif
#pragma unroll
        for (int i = 0; i < 4; i++) { Ag[i] += 64; Bg[i] += 64; }
        __syncthreads();
#pragma unroll
        for (int km = 0; km < 2; km++) {
            bf16x8 af[4], bfr[4];
#pragma unroll
            for (int mt = 0; mt < 4; mt++)
                af[mt] = *(const bf16x8*)(Alds + ((wm4 + mt) * 2 + km) * 512 + l * 8);
#pragma unroll
            for (int nt = 0; nt < 4; nt++)
                bfr[nt] = *(const bf16x8*)(Blds + ((wn4 + nt) * 2 + km) * 512 + l * 8);
#pragma unroll
            for (int mt = 0; mt < 4; mt++)
#pragma unroll
                for (int nt = 0; nt < 4; nt++)
                    acc[mt][nt] = __builtin_amdgcn_mfma_f32_16x16x32_bf16(
                        af[mt], bfr[nt], acc[mt][nt], 0, 0, 0);
        }
        __syncthreads();
    }

    float bv[4];
#pragma unroll
    for (int nt = 0; nt < 4; nt++)
        bv[nt] = BIAS ? bias[colL + wn4 * 16 + nt * 16 + lc] : 0.f;

#pragma unroll
    for (int mt = 0; mt < 4; mt++) {
        const int rowb = row0 + wm4 * 16 + mt * 16 + lq * 4;
#pragma unroll
        for (int nt = 0; nt < 4; nt++) {
            const int col = colL + wn4 * 16 + nt * 16 + lc;
            float v[4];
#pragma unroll
            for (int r = 0; r < 4; r++) {
                float xv = acc[mt][nt][r] + bv[nt];
                if (RELU) xv = fmaxf(xv, 0.f);
                v[r] = (((rowb + r) & (Lv - 1)) >= len) ? 0.f : xv;
            }
            if (tr) {
                uint2 o = {pack2(v[0], v[1]), pack2(v[2], v[3])};
                *(uint2*)(C + (size_t)col * Mv + rowb) = o;
            } else {
#pragma unroll
                for (int r = 0; r < 4; r++)
                    C[(size_t)(rowb + r) * Ev + col] = f2bf(v[r]);
            }
        }
    }
}

// ---- MFMA flash attention. 128 q/block, 4 waves x 32 q (2 m-tiles), 128-key
//      tiles, K/V/P fragment-ordered LDS, async staging, online softmax. ----
template <int CAUSAL>
__global__ __launch_bounds__(256) void mattn(u16* __restrict__ QZ,
                                             const u16* __restrict__ K,
                                             const u16* __restrict__ VT,
                                             const int* __restrict__ lens) {
    __shared__ u16 Kt[16 * 512];
    __shared__ u16 Vt[16 * 512];
    __shared__ u16 Pt[4 * 4 * 512];
    const int b = blockIdx.z, h = blockIdx.y, qb = blockIdx.x;
    const int q0 = qb * 128;
    const int tid = threadIdx.x;
    const int w = tid >> 6, l = tid & 63;
    const int lc = l & 15, lq = l >> 4;
    int len = lens[b];
    len = min(max(len, 0), Lv);

    if (q0 >= len) {
        const int zr = tid >> 1, zc = (tid & 1) * 32;
        uint4 z4 = {0u, 0u, 0u, 0u};
        uint4* p = (uint4*)(QZ + (size_t)(b * Lv + q0 + zr) * Ev + h * DKv + zc);
        p[0] = z4; p[1] = z4; p[2] = z4; p[3] = z4;
        return;
    }

    bf16x8 qf[2][2];
#pragma unroll
    for (int mt = 0; mt < 2; mt++)
#pragma unroll
        for (int k2 = 0; k2 < 2; k2++)
            qf[mt][k2] = *(const bf16x8*)(QZ + (size_t)(b * Lv + q0 + w * 32 + mt * 16 + lc) * Ev +
                                          h * DKv + k2 * 32 + lq * 8);

    f32x4 of[2][4];
#pragma unroll
    for (int mt = 0; mt < 2; mt++)
#pragma unroll
        for (int nd = 0; nd < 4; nd++) of[mt][nd] = (f32x4){0.f, 0.f, 0.f, 0.f};
    float mrow[2][4], lrow[2][4];
#pragma unroll
    for (int mt = 0; mt < 2; mt++)
#pragma unroll
        for (int r = 0; r < 4; r++) { mrow[mt][r] = -1e30f; lrow[mt][r] = 0.f; }

    const u16* Kg[4]; const u16* Vg[4]; u16* Kl[4]; u16* Vl[4];
#pragma unroll
    for (int i = 0; i < 4; i++) {
        const int k16 = 2 * w + (i >> 1), d32 = i & 1;
        Kg[i] = K + (size_t)(b * Lv + k16 * 16 + lc) * Ev + h * DKv + d32 * 32 + lq * 8;
        Kl[i] = Kt + (k16 * 2 + d32) * 512;
        Vg[i] = VT + (size_t)(h * DKv + w * 16 + lc) * Mv + b * Lv + i * 32 + lq * 8;
        Vl[i] = Vt + (w * 4 + i) * 512;
    }
    u16* Pw = Pt + w * 2048;

    const int jend = CAUSAL ? min(len, q0 + 128) : len;
    const int ntiles = (jend + 127) >> 7;

    for (int kt = 0; kt < ntiles; kt++) {
        const int koff = kt * 128;
#if HAS_GLL
#pragma unroll
        for (int i = 0; i < 4; i++) {
            gll16(Kg[i] + (size_t)koff * Ev, Kl[i]);
            gll16(Vg[i] + koff, Vl[i]);
        }
#else
#pragma unroll
        for (int i = 0; i < 4; i++) {
            *(uint4*)(Kl[i] + l * 8) = *(const uint4*)(Kg[i] + (size_t)koff * Ev);
            *(uint4*)(Vl[i] + l * 8) = *(const uint4*)(Vg[i] + koff);
        }
#endif
        __syncthreads();

        f32x4 sf[2][8];
#pragma unroll
        for (int nt = 0; nt < 8; nt++) {
            bf16x8 kf0 = *(const bf16x8*)(Kt + (nt * 2 + 0) * 512 + l * 8);
            bf16x8 kf1 = *(const bf16x8*)(Kt + (nt * 2 + 1) * 512 + l * 8);
#pragma unroll
            for (int mt = 0; mt < 2; mt++) {
                f32x4 s = (f32x4){0.f, 0.f, 0.f, 0.f};
                s = __builtin_amdgcn_mfma_f32_16x16x32_bf16(qf[mt][0], kf0, s, 0, 0, 0);
                s = __builtin_amdgcn_mfma_f32_16x16x32_bf16(qf[mt][1], kf1, s, 0, 0, 0);
                sf[mt][nt] = s;
            }
        }

        float alpha[2][4];
#pragma unroll
        for (int mt = 0; mt < 2; mt++) {
            float tmax[4] = {-1e30f, -1e30f, -1e30f, -1e30f};
#pragma unroll
            for (int nt = 0; nt < 8; nt++) {
                const int jj = koff + nt * 16 + lc;
                const bool jv = jj < len;
#pragma unroll
                for (int r = 0; r < 4; r++) {
                    const int iq = q0 + w * 32 + mt * 16 + lq * 4 + r;
                    const bool valid = jv && (!CAUSAL || jj <= iq);
                    float e = valid ? sf[mt][nt][r] * 0.125f : -1e30f;
                    sf[mt][nt][r] = e;
                    tmax[r] = fmaxf(tmax[r], e);
                }
            }
#pragma unroll
            for (int r = 0; r < 4; r++) {
#pragma unroll
                for (int d = 1; d < 16; d <<= 1)
                    tmax[r] = fmaxf(tmax[r], __shfl_xor(tmax[r], d, 64));
            }
            float psum[4];
#pragma unroll
            for (int r = 0; r < 4; r++) {
                const float mn = fmaxf(mrow[mt][r], tmax[r]);
                alpha[mt][r] = __expf(mrow[mt][r] - mn);
                mrow[mt][r] = mn;
                psum[r] = 0.f;
            }
#pragma unroll
            for (int nt = 0; nt < 8; nt++)
#pragma unroll
                for (int r = 0; r < 4; r++) {
                    float p = __expf(sf[mt][nt][r] - mrow[mt][r]);
                    sf[mt][nt][r] = p;
                    psum[r] += p;
                }
#pragma unroll
            for (int r = 0; r < 4; r++) {
#pragma unroll
                for (int d = 1; d < 16; d <<= 1) psum[r] += __shfl_xor(psum[r], d, 64);
                lrow[mt][r] = lrow[mt][r] * alpha[mt][r] + psum[r];
            }
#pragma unroll
            for (int nd = 0; nd < 4; nd++)
#pragma unroll
                for (int r = 0; r < 4; r++) of[mt][nd][r] *= alpha[mt][r];
        }

#pragma unroll
        for (int mt = 0; mt < 2; mt++) {
#pragma unroll
            for (int nt = 0; nt < 8; nt++)
#pragma unroll
                for (int r = 0; r < 4; r++)
                    Pw[(nt >> 1) * 512 +
                       ((2 * (nt & 1) + (lc >> 3)) * 16 + lq * 4 + r) * 8 + (lc & 7)] =
                        f2bf(sf[mt][nt][r]);
#pragma unroll
            for (int km = 0; km < 4; km++) {
                bf16x8 pa = *(const bf16x8*)(Pw + km * 512 + l * 8);
#pragma unroll
                for (int nd = 0; nd < 4; nd++) {
                    bf16x8 vb = *(const bf16x8*)(Vt + (nd * 4 + km) * 512 + l * 8);
                    of[mt][nd] = __builtin_amdgcn_mfma_f32_16x16x32_bf16(pa, vb, of[mt][nd], 0, 0, 0);
                }
            }
        }
        __syncthreads();
    }

#pragma unroll
    for (int mt = 0; mt < 2; mt++) {
        float inv[4];
#pragma unroll
        for (int r = 0; r < 4; r++) {
            const int iq = q0 + w * 32 + mt * 16 + lq * 4 + r;
            inv[r] = (iq < len && lrow[mt][r] > 0.f) ? (1.f / lrow[mt][r]) : 0.f;
        }
#pragma unroll
        for (int nd = 0; nd < 4; nd++)
#pragma unroll
            for (int r = 0; r < 4; r++)
                QZ[(size_t)(b * Lv + q0 + w * 32 + mt * 16 + lq * 4 + r) * Ev +
                   h * DKv + nd * 16 + lc] = f2bf(of[mt][nd][r] * inv[r]);
    }
}

// ---- residual + LayerNorm, shuffle reduction: out = LN(base + z)*g + b. ----
template <int BASEBF, int OUTF32>
__global__ __launch_bounds__(256) void ln_k(const void* __restrict__ base,
                                            const u16* __restrict__ z,
                                            const float* __restrict__ g,
                                            const float* __restrict__ bta,
                                            void* __restrict__ out) {
    __shared__ float w1[4], w2[4];
    const int row = blockIdx.x, t = threadIdx.x;
    const int w = t >> 6, l = t & 63;
    const int c0 = t * 4;
    float v[4];
    if (BASEBF) {
        uint2 bu = *(const uint2*)((const u16*)base + (size_t)row * Ev + c0);
        v[0] = bf_lo(bu.x); v[1] = bf_hi(bu.x); v[2] = bf_lo(bu.y); v[3] = bf_hi(bu.y);
    } else {
        float4 f = *(const float4*)((const float*)base + (size_t)row * Ev + c0);
        v[0] = f.x; v[1] = f.y; v[2] = f.z; v[3] = f.w;
    }
    uint2 zu = *(const uint2*)(z + (size_t)row * Ev + c0);
    v[0] += bf_lo(zu.x); v[1] += bf_hi(zu.x); v[2] += bf_lo(zu.y); v[3] += bf_hi(zu.y);
    float s1 = v[0] + v[1] + v[2] + v[3];
    float s2 = v[0] * v[0] + v[1] * v[1] + v[2] * v[2] + v[3] * v[3];
#pragma unroll
    for (int d = 1; d < 64; d <<= 1) {
        s1 += __shfl_xor(s1, d, 64);
        s2 += __shfl_xor(s2, d, 64);
    }
    if (l == 0) { w1[w] = s1; w2[w] = s2; }
    __syncthreads();
    s1 = w1[0] + w1[1] + w1[2] + w1[3];
    s2 = w2[0] + w2[1] + w2[2] + w2[3];
    const float mu = s1 * (1.f / Ev);
    const float var = s2 * (1.f / Ev) - mu * mu;
    const float rinv = rsqrtf(fmaxf(var, 0.f) + 1e-5f);
    float4 gv = *(const float4*)(g + c0);
    float4 bv = *(const float4*)(bta + c0);
    float y[4];
    y[0] = (v[0] - mu) * rinv * gv.x + bv.x;
    y[1] = (v[1] - mu) * rinv * gv.y + bv.y;
    y[2] = (v[2] - mu) * rinv * gv.z + bv.z;
    y[3] = (v[3] - mu) * rinv * gv.w + bv.w;
    if (OUTF32) {
        float4 ow = {y[0], y[1], y[2], y[3]};
        *(float4*)((float*)out + (size_t)row * Ev + c0) = ow;
    } else {
        uint2 ow = {pack2(y[0], y[1]), pack2(y[2], y[3])};
        *(uint2*)((u16*)out + (size_t)row * Ev + c0) = ow;
    }
}

extern "C" void kernel_launch(void* const* d_in, const int* in_sizes, int n_in,
                              void* d_out, int out_size, void* d_ws, size_t ws_size,
                              hipStream_t stream) {
    const float* x    = (const float*)d_in[0];
    const float* ctx  = (const float*)d_in[1];
    const int*   lens = (const int*)d_in[2];
    const float* Wq1 = (const float*)d_in[4];
    const float* Wk1 = (const float*)d_in[5];
    const float* Wv1 = (const float*)d_in[6];
    const float* Wq2 = (const float*)d_in[7];
    const float* Wk2 = (const float*)d_in[8];
    const float* Wv2 = (const float*)d_in[9];
    const float* g1 = (const float*)d_in[10], *b1 = (const float*)d_in[11];
    const float* g2 = (const float*)d_in[12], *b2 = (const float*)d_in[13];
    const float* g3 = (const float*)d_in[14], *b3 = (const float*)d_in[15];
    const float* fc1w = (const float*)d_in[16], *fc1b = (const float*)d_in[17];
    const float* fc2w = (const float*)d_in[18], *fc2b = (const float*)d_in[19];

    const size_t WSZ = (size_t)Ev * Ev;
    const size_t MM  = (size_t)Mv * Ev;
    u16* WT = (u16*)d_ws;                // q1,k1,v1,q2,k2,v2,f1,f2 contiguous
    u16* Wtq1 = WT + 0 * WSZ;
    u16* Wtq2 = WT + 3 * WSZ, *Wtv2 = WT + 5 * WSZ;
    u16* Wtf1 = WT + 6 * WSZ, *Wtf2 = WT + 7 * WSZ;
    u16* B1 = WT + 8 * WSZ;
    u16* B2 = B1 + MM;
    u16* B3 = B2 + MM;
    u16* B4 = B3 + MM;
    u16* xb = (u16*)d_out;               // bf16 x/ctx parked in d_out until final LN
    u16* cb = xb + MM;

    dim3 gP(24576), gQKV(24, 64), gQK(16, 64), gG1(8, 64), gA(8, Hv, Bv), gL(Mv);

    prep_k<<<gP, 256, 0, stream>>>(x, ctx, Wq1, Wk1, Wv1, Wq2, Wk2, Wv2, fc1w, fc2w,
                                   xb, cb, WT);

    // self-attention (causal): fused Q/K/V^T projection, then flash
    mgemm<0, 0, 2><<<gQKV, 256, 0, stream>>>(xb, Wtq1, nullptr, B1, B2, B3, lens);
    mattn<1><<<gA, 256, 0, stream>>>(B1, B2, B3, lens);                 // Z1 -> B1
    ln_k<0, 0><<<gL, 256, 0, stream>>>(x, B1, g1, b1, B2);              // X1 -> B2

    // cross-attention: fused Q/K from ctx; V^T from X1
    mgemm<0, 0, -1><<<gQK, 256, 0, stream>>>(cb, Wtq2, nullptr, B1, B3, nullptr, lens);
    mgemm<0, 0, 0><<<gG1, 256, 0, stream>>>(B2, Wtv2, nullptr, B4, nullptr, nullptr, lens);
    mattn<0><<<gA, 256, 0, stream>>>(B1, B3, B4, lens);                 // Z2 -> B1
    ln_k<1, 0><<<gL, 256, 0, stream>>>(B2, B1, g2, b2, B3);             // X2 -> B3

    // FFN
    mgemm<1, 1, -1><<<gG1, 256, 0, stream>>>(B3, Wtf1, fc1b, B1, nullptr, nullptr, lens); // H
    mgemm<1, 0, -1><<<gG1, 256, 0, stream>>>(B1, Wtf2, fc2b, B2, nullptr, nullptr, lens); // Z3
    ln_k<1, 1><<<gL, 256, 0, stream>>>(B3, B2, g3, b3, d_out);          // final (fp32)
}